// Round 1
// baseline (745.129 us; speedup 1.0000x reference)
//
#include <hip/hip_runtime.h>
#include <hip/hip_bf16.h>
#include <cstdint>

typedef unsigned short u16;
typedef unsigned int u32;

#define BB   4
#define SSQ  1024
#define HHD  1024
#define HNN  16
#define DDIM 64
#define MM   (BB*SSQ)                 // 4096 rows of X
#define OUT0_ELEMS ((size_t)MM*HHD)   // 4,194,304

typedef __attribute__((ext_vector_type(8))) short  short8;
typedef __attribute__((ext_vector_type(8))) __bf16 bf16x8;
typedef __attribute__((ext_vector_type(4))) float  f32x4;
typedef __attribute__((ext_vector_type(4))) u16    u16x4;

__device__ __forceinline__ u16 f2b(float f) {
    u32 u = __builtin_bit_cast(u32, f);
    u += 0x7FFFu + ((u >> 16) & 1u);
    return (u16)(u >> 16);
}
__device__ __forceinline__ bf16x8 ld8(const u16* p) {
    return *(const bf16x8*)p;
}
__device__ __forceinline__ f32x4 mfma16(bf16x8 a, bf16x8 b, f32x4 c) {
    return __builtin_amdgcn_mfma_f32_16x16x32_bf16(a, b, c, 0, 0, 0);
}

// ---------------- conversion kernels ----------------
// cast query/key/value (f32, [4096,1024]) -> bf16, z selects tensor
__global__ void conv_x(const float* __restrict__ q, const float* __restrict__ k,
                       const float* __restrict__ v, u16* __restrict__ out) {
    int z = blockIdx.z;
    const float* src = (z == 0) ? q : (z == 1) ? k : v;
    size_t i = (size_t)blockIdx.x * blockDim.x + threadIdx.x;   // over 1M float4
    f32x4 f = ((const f32x4*)src)[i];
    u16x4 o;
    o[0] = f2b(f[0]); o[1] = f2b(f[1]); o[2] = f2b(f[2]); o[3] = f2b(f[3]);
    ((u16x4*)(out + (size_t)z * MM * HHD))[i] = o;
}

// transpose-cast W [k][n] f32 -> Wt [n][k] bf16 (z = Wq,Wk,Wv,Wo)
__global__ void conv_wt(const float* __restrict__ w0, const float* __restrict__ w1,
                        const float* __restrict__ w2, const float* __restrict__ w3,
                        u16* __restrict__ out) {
    __shared__ float t[32][33];
    int z = blockIdx.z;
    const float* src = (z == 0) ? w0 : (z == 1) ? w1 : (z == 2) ? w2 : w3;
    int k0 = blockIdx.y * 32, n0 = blockIdx.x * 32;
    int tx = threadIdx.x, ty = threadIdx.y;     // 32 x 8
    for (int i = ty; i < 32; i += 8)
        t[i][tx] = src[(size_t)(k0 + i) * HHD + n0 + tx];
    __syncthreads();
    u16* dst = out + (size_t)z * HHD * HHD;
    for (int i = ty; i < 32; i += 8)
        dst[(size_t)(n0 + i) * HHD + k0 + tx] = f2b(t[tx][i]);
}

// ---------------- QKV projection GEMM ----------------
// C[4096,1024] = X@W + bias.  z: 0=q -> qh[b,h,s,d], 1=k -> kh[b,h,s,d], 2=v -> vt[b,h,d,s]
__global__ __launch_bounds__(256) void gemm_xw(
        const u16* __restrict__ Xb, const u16* __restrict__ Wt,
        const float* __restrict__ bq, const float* __restrict__ bk,
        const float* __restrict__ bv,
        u16* __restrict__ qh, u16* __restrict__ kh, u16* __restrict__ vt) {
    int z = blockIdx.z;
    const u16* X = Xb + (size_t)z * MM * HHD;
    const u16* W = Wt + (size_t)z * HHD * HHD;
    const float* bias = (z == 0) ? bq : (z == 1) ? bk : bv;
    int lane = threadIdx.x & 63, w = threadIdx.x >> 6;
    int wm = w >> 1, wn = w & 1;
    int rbase = blockIdx.y * 128 + wm * 64;
    int cbase = blockIdx.x * 128 + wn * 64;
    int lr = lane & 15, lg = lane >> 4;
    f32x4 acc[4][4] = {};
    for (int k0 = 0; k0 < HHD; k0 += 32) {
        bf16x8 a[4], b[4];
#pragma unroll
        for (int i = 0; i < 4; i++)
            a[i] = ld8(X + (size_t)(rbase + i * 16 + lr) * HHD + k0 + lg * 8);
#pragma unroll
        for (int j = 0; j < 4; j++)
            b[j] = ld8(W + (size_t)(cbase + j * 16 + lr) * HHD + k0 + lg * 8);
#pragma unroll
        for (int i = 0; i < 4; i++)
#pragma unroll
            for (int j = 0; j < 4; j++)
                acc[i][j] = mfma16(a[i], b[j], acc[i][j]);
    }
#pragma unroll
    for (int i = 0; i < 4; i++)
#pragma unroll
        for (int j = 0; j < 4; j++) {
            int col = cbase + j * 16 + lr;
            float bval = bias[col];
            int h = col >> 6, d = col & 63;
#pragma unroll
            for (int e = 0; e < 4; e++) {
                int row = rbase + i * 16 + lg * 4 + e;
                int bidx = row >> 10, s = row & 1023;
                u16 o = f2b(acc[i][j][e] + bval);
                if (z == 0)
                    qh[(((size_t)bidx * HNN + h) * SSQ + s) * DDIM + d] = o;
                else if (z == 1)
                    kh[(((size_t)bidx * HNN + h) * SSQ + s) * DDIM + d] = o;
                else
                    vt[(((size_t)bidx * HNN + h) * DDIM + d) * SSQ + s] = o;
            }
        }
}

// ---------------- scores = (q k^T + pb)/8 + mask + prev ----------------
__global__ __launch_bounds__(256) void attn_scores(
        const u16* __restrict__ qh, const u16* __restrict__ kh,
        const float* __restrict__ pb, const float* __restrict__ mask,
        const float* __restrict__ prev, float* __restrict__ out) {
    int bh = blockIdx.z;
    int b = bh >> 4, h = bh & 15;
    const u16* Q = qh + (size_t)bh * SSQ * DDIM;
    const u16* K = kh + (size_t)bh * SSQ * DDIM;
    int lane = threadIdx.x & 63, w = threadIdx.x >> 6;
    int wm = w >> 1, wn = w & 1;
    int rbase = blockIdx.y * 128 + wm * 64;
    int cbase = blockIdx.x * 128 + wn * 64;
    int lr = lane & 15, lg = lane >> 4;
    f32x4 acc[4][4] = {};
#pragma unroll
    for (int k0 = 0; k0 < DDIM; k0 += 32) {
        bf16x8 a[4], bfr[4];
#pragma unroll
        for (int i = 0; i < 4; i++)
            a[i] = ld8(Q + (size_t)(rbase + i * 16 + lr) * DDIM + k0 + lg * 8);
#pragma unroll
        for (int j = 0; j < 4; j++)
            bfr[j] = ld8(K + (size_t)(cbase + j * 16 + lr) * DDIM + k0 + lg * 8);
#pragma unroll
        for (int i = 0; i < 4; i++)
#pragma unroll
            for (int j = 0; j < 4; j++)
                acc[i][j] = mfma16(a[i], bfr[j], acc[i][j]);
    }
    const float* pbh = pb + (size_t)h * SSQ * SSQ;
    const float* mb  = mask + (size_t)b * SSQ * SSQ;
    const float* pr  = prev + (size_t)bh * SSQ * SSQ;
    float* ob = out + (size_t)bh * SSQ * SSQ;
#pragma unroll
    for (int i = 0; i < 4; i++)
#pragma unroll
        for (int j = 0; j < 4; j++) {
            int col = cbase + j * 16 + lr;
#pragma unroll
            for (int e = 0; e < 4; e++) {
                int row = rbase + i * 16 + lg * 4 + e;
                size_t idx = (size_t)row * SSQ + col;
                ob[idx] = (acc[i][j][e] + pbh[idx]) * 0.125f + mb[idx] + pr[idx];
            }
        }
}

// ---------------- row max / sum(exp) ----------------
__global__ __launch_bounds__(256) void row_stats(
        const float* __restrict__ sc, float* __restrict__ mrow, float* __restrict__ lrow) {
    int bh = blockIdx.y;
    int w = threadIdx.x >> 6, lane = threadIdx.x & 63;
    int row = blockIdx.x * 4 + w;
    const f32x4* p = (const f32x4*)(sc + (size_t)bh * SSQ * SSQ + (size_t)row * SSQ);
    f32x4 vals[4];
    float m = -3.4e38f;
#pragma unroll
    for (int t = 0; t < 4; t++) {
        vals[t] = p[lane + 64 * t];
#pragma unroll
        for (int c = 0; c < 4; c++) m = fmaxf(m, vals[t][c]);
    }
#pragma unroll
    for (int off = 32; off >= 1; off >>= 1) m = fmaxf(m, __shfl_xor(m, off));
    float sum = 0.f;
#pragma unroll
    for (int t = 0; t < 4; t++)
#pragma unroll
        for (int c = 0; c < 4; c++) sum += __expf(vals[t][c] - m);
#pragma unroll
    for (int off = 32; off >= 1; off >>= 1) sum += __shfl_xor(sum, off);
    if (lane == 0) {
        mrow[(size_t)bh * SSQ + row] = m;
        lrow[(size_t)bh * SSQ + row] = sum;
    }
}

// ---------------- PV: ctx[s][h*64+d] = softmax(scores) @ v ----------------
__global__ __launch_bounds__(256) void pv_ctx(
        const float* __restrict__ sc, const float* __restrict__ mrow,
        const float* __restrict__ lrow, const u16* __restrict__ vt,
        u16* __restrict__ ctx) {
    int bh = blockIdx.y;
    int b = bh >> 4, h = bh & 15;
    int lane = threadIdx.x & 63, w = threadIdx.x >> 6;
    int lr = lane & 15, lg = lane >> 4;
    int rbase = blockIdx.x * 128 + w * 32;
    const float* sb = sc + (size_t)bh * SSQ * SSQ;
    const u16* vb = vt + (size_t)bh * DDIM * SSQ;
    float mr[2];
    mr[0] = mrow[(size_t)bh * SSQ + rbase + lr];
    mr[1] = mrow[(size_t)bh * SSQ + rbase + 16 + lr];
    f32x4 acc[2][4] = {};
    for (int k0 = 0; k0 < SSQ; k0 += 32) {
        bf16x8 a[2];
#pragma unroll
        for (int am = 0; am < 2; am++) {
            const float* sp = sb + (size_t)(rbase + am * 16 + lr) * SSQ + k0 + lg * 8;
            f32x4 x0 = *(const f32x4*)sp;
            f32x4 x1 = *(const f32x4*)(sp + 4);
            short8 pk;
#pragma unroll
            for (int c = 0; c < 4; c++) pk[c]     = (short)f2b(__expf(x0[c] - mr[am]));
#pragma unroll
            for (int c = 0; c < 4; c++) pk[4 + c] = (short)f2b(__expf(x1[c] - mr[am]));
            a[am] = __builtin_bit_cast(bf16x8, pk);
        }
        bf16x8 bfr[4];
#pragma unroll
        for (int j = 0; j < 4; j++)
            bfr[j] = ld8(vb + (size_t)(j * 16 + lr) * SSQ + k0 + lg * 8);
#pragma unroll
        for (int am = 0; am < 2; am++)
#pragma unroll
            for (int j = 0; j < 4; j++)
                acc[am][j] = mfma16(a[am], bfr[j], acc[am][j]);
    }
    float linv[2][4];
#pragma unroll
    for (int am = 0; am < 2; am++)
#pragma unroll
        for (int e = 0; e < 4; e++)
            linv[am][e] = 1.f / lrow[(size_t)bh * SSQ + rbase + am * 16 + lg * 4 + e];
#pragma unroll
    for (int am = 0; am < 2; am++)
#pragma unroll
        for (int j = 0; j < 4; j++) {
            int d = j * 16 + lr;
#pragma unroll
            for (int e = 0; e < 4; e++) {
                int row = rbase + am * 16 + lg * 4 + e;
                ctx[((size_t)(b * SSQ + row)) * HHD + h * DDIM + d] =
                    f2b(acc[am][j][e] * linv[am][e]);
            }
        }
}

// ---------------- output projection ----------------
__global__ __launch_bounds__(256) void gemm_out(
        const u16* __restrict__ ctxb, const u16* __restrict__ WtO,
        const float* __restrict__ bo, float* __restrict__ out) {
    int lane = threadIdx.x & 63, w = threadIdx.x >> 6;
    int wm = w >> 1, wn = w & 1;
    int rbase = blockIdx.y * 128 + wm * 64;
    int cbase = blockIdx.x * 128 + wn * 64;
    int lr = lane & 15, lg = lane >> 4;
    f32x4 acc[4][4] = {};
    for (int k0 = 0; k0 < HHD; k0 += 32) {
        bf16x8 a[4], b[4];
#pragma unroll
        for (int i = 0; i < 4; i++)
            a[i] = ld8(ctxb + (size_t)(rbase + i * 16 + lr) * HHD + k0 + lg * 8);
#pragma unroll
        for (int j = 0; j < 4; j++)
            b[j] = ld8(WtO + (size_t)(cbase + j * 16 + lr) * HHD + k0 + lg * 8);
#pragma unroll
        for (int i = 0; i < 4; i++)
#pragma unroll
            for (int j = 0; j < 4; j++)
                acc[i][j] = mfma16(a[i], b[j], acc[i][j]);
    }
#pragma unroll
    for (int i = 0; i < 4; i++)
#pragma unroll
        for (int j = 0; j < 4; j++) {
            int col = cbase + j * 16 + lr;
            float bval = bo[col];
#pragma unroll
            for (int e = 0; e < 4; e++) {
                int row = rbase + i * 16 + lg * 4 + e;
                out[(size_t)row * HHD + col] = acc[i][j][e] + bval;
            }
        }
}

extern "C" void kernel_launch(void* const* d_in, const int* in_sizes, int n_in,
                              void* d_out, int out_size, void* d_ws, size_t ws_size,
                              hipStream_t stream) {
    const float* key   = (const float*)d_in[0];
    const float* value = (const float*)d_in[1];
    const float* query = (const float*)d_in[2];
    const float* mask  = (const float*)d_in[3];
    const float* pb    = (const float*)d_in[4];
    const float* prev  = (const float*)d_in[5];
    const float* Wq    = (const float*)d_in[6];
    const float* bq    = (const float*)d_in[7];
    const float* Wk    = (const float*)d_in[8];
    const float* bk    = (const float*)d_in[9];
    const float* Wv    = (const float*)d_in[10];
    const float* bv    = (const float*)d_in[11];
    const float* Wo    = (const float*)d_in[12];
    const float* bo    = (const float*)d_in[13];

    u16* Xb  = (u16*)d_ws;                      // 3 * 4M bf16
    u16* Wt  = Xb + (size_t)3 * MM * HHD;       // 4 * 1M bf16
    u16* qh  = Wt + (size_t)4 * HHD * HHD;      // 4M
    u16* kh  = qh + (size_t)MM * HHD;           // 4M
    u16* vt  = kh + (size_t)MM * HHD;           // 4M
    u16* ctx = vt + (size_t)MM * HHD;           // 4M
    float* mrow = (float*)(ctx + (size_t)MM * HHD);   // 64K f32
    float* lrow = mrow + (size_t)64 * SSQ;            // 64K f32

    float* out0 = (float*)d_out;
    float* sc   = out0 + OUT0_ELEMS;            // prev_attn_out region

    conv_x<<<dim3(4096, 1, 3), 256, 0, stream>>>(query, key, value, Xb);
    conv_wt<<<dim3(32, 32, 4), dim3(32, 8), 0, stream>>>(Wq, Wk, Wv, Wo, Wt);
    gemm_xw<<<dim3(8, 32, 3), 256, 0, stream>>>(Xb, Wt, bq, bk, bv, qh, kh, vt);
    attn_scores<<<dim3(8, 8, 64), 256, 0, stream>>>(qh, kh, pb, mask, prev, sc);
    row_stats<<<dim3(256, 64), 256, 0, stream>>>(sc, mrow, lrow);
    pv_ctx<<<dim3(8, 64), 256, 0, stream>>>(sc, mrow, lrow, vt, ctx);
    gemm_out<<<dim3(8, 32), 256, 0, stream>>>(ctx, Wt + (size_t)3 * HHD * HHD, bo, out0);
}

// Round 2
// 468.967 us; speedup vs baseline: 1.5889x; 1.5889x over previous
//
#include <hip/hip_runtime.h>
#include <hip/hip_bf16.h>
#include <cstdint>

typedef unsigned short u16;
typedef unsigned int u32;

#define BB   4
#define SSQ  1024
#define HHD  1024
#define HNN  16
#define DDIM 64
#define MM   (BB*SSQ)                 // 4096 rows of X
#define OUT0_ELEMS ((size_t)MM*HHD)   // 4,194,304

typedef __attribute__((ext_vector_type(8))) short  short8;
typedef __attribute__((ext_vector_type(8))) __bf16 bf16x8;
typedef __attribute__((ext_vector_type(4))) float  f32x4;
typedef __attribute__((ext_vector_type(4))) u16    u16x4;

__device__ __forceinline__ u16 f2b(float f) {
    u32 u = __builtin_bit_cast(u32, f);
    u += 0x7FFFu + ((u >> 16) & 1u);
    return (u16)(u >> 16);
}
__device__ __forceinline__ bf16x8 ld8(const u16* p) {
    return *(const bf16x8*)p;
}
__device__ __forceinline__ f32x4 mfma16(bf16x8 a, bf16x8 b, f32x4 c) {
    return __builtin_amdgcn_mfma_f32_16x16x32_bf16(a, b, c, 0, 0, 0);
}

// ---------------- conversion kernels ----------------
__global__ void conv_x(const float* __restrict__ q, const float* __restrict__ k,
                       const float* __restrict__ v, u16* __restrict__ out) {
    int z = blockIdx.z;
    const float* src = (z == 0) ? q : (z == 1) ? k : v;
    size_t i = (size_t)blockIdx.x * blockDim.x + threadIdx.x;   // over 1M float4
    f32x4 f = ((const f32x4*)src)[i];
    u16x4 o;
    o[0] = f2b(f[0]); o[1] = f2b(f[1]); o[2] = f2b(f[2]); o[3] = f2b(f[3]);
    ((u16x4*)(out + (size_t)z * MM * HHD))[i] = o;
}

__global__ void conv_wt(const float* __restrict__ w0, const float* __restrict__ w1,
                        const float* __restrict__ w2, const float* __restrict__ w3,
                        u16* __restrict__ out) {
    __shared__ float t[32][33];
    int z = blockIdx.z;
    const float* src = (z == 0) ? w0 : (z == 1) ? w1 : (z == 2) ? w2 : w3;
    int k0 = blockIdx.y * 32, n0 = blockIdx.x * 32;
    int tx = threadIdx.x, ty = threadIdx.y;     // 32 x 8
    for (int i = ty; i < 32; i += 8)
        t[i][tx] = src[(size_t)(k0 + i) * HHD + n0 + tx];
    __syncthreads();
    u16* dst = out + (size_t)z * HHD * HHD;
    for (int i = ty; i < 32; i += 8)
        dst[(size_t)(n0 + i) * HHD + k0 + tx] = f2b(t[tx][i]);
}

// ---------------- QKV projection GEMM ----------------
__global__ __launch_bounds__(256) void gemm_xw(
        const u16* __restrict__ Xb, const u16* __restrict__ Wt,
        const float* __restrict__ bq, const float* __restrict__ bk,
        const float* __restrict__ bv,
        u16* __restrict__ qh, u16* __restrict__ kh, u16* __restrict__ vt) {
    int z = blockIdx.z;
    const u16* X = Xb + (size_t)z * MM * HHD;
    const u16* W = Wt + (size_t)z * HHD * HHD;
    const float* bias = (z == 0) ? bq : (z == 1) ? bk : bv;
    int lane = threadIdx.x & 63, w = threadIdx.x >> 6;
    int wm = w >> 1, wn = w & 1;
    int rbase = blockIdx.y * 128 + wm * 64;
    int cbase = blockIdx.x * 128 + wn * 64;
    int lr = lane & 15, lg = lane >> 4;
    f32x4 acc[4][4] = {};
    for (int k0 = 0; k0 < HHD; k0 += 32) {
        bf16x8 a[4], b[4];
#pragma unroll
        for (int i = 0; i < 4; i++)
            a[i] = ld8(X + (size_t)(rbase + i * 16 + lr) * HHD + k0 + lg * 8);
#pragma unroll
        for (int j = 0; j < 4; j++)
            b[j] = ld8(W + (size_t)(cbase + j * 16 + lr) * HHD + k0 + lg * 8);
#pragma unroll
        for (int i = 0; i < 4; i++)
#pragma unroll
            for (int j = 0; j < 4; j++)
                acc[i][j] = mfma16(a[i], b[j], acc[i][j]);
    }
#pragma unroll
    for (int i = 0; i < 4; i++)
#pragma unroll
        for (int j = 0; j < 4; j++) {
            int col = cbase + j * 16 + lr;
            float bval = bias[col];
            int h = col >> 6, d = col & 63;
#pragma unroll
            for (int e = 0; e < 4; e++) {
                int row = rbase + i * 16 + lg * 4 + e;
                int bidx = row >> 10, s = row & 1023;
                u16 o = f2b(acc[i][j][e] + bval);
                if (z == 0)
                    qh[(((size_t)bidx * HNN + h) * SSQ + s) * DDIM + d] = o;
                else if (z == 1)
                    kh[(((size_t)bidx * HNN + h) * SSQ + s) * DDIM + d] = o;
                else
                    vt[(((size_t)bidx * HNN + h) * DDIM + d) * SSQ + s] = o;
            }
        }
}

// ---------------- scores = (q k^T + pb)/8 + mask + prev, + partial softmax stats ----------------
// LDS round-trip so all global traffic in the epilogue is f32x4-coalesced.
__global__ __launch_bounds__(256) void attn_scores(
        const u16* __restrict__ qh, const u16* __restrict__ kh,
        const float* __restrict__ pb, const float* __restrict__ mask,
        const float* __restrict__ prev, float* __restrict__ out,
        float* __restrict__ pm, float* __restrict__ pl) {
    __shared__ float sl[128 * 128];   // 64 KB score tile
    int bh = blockIdx.z;
    int b = bh >> 4, h = bh & 15;
    const u16* Q = qh + (size_t)bh * SSQ * DDIM;
    const u16* K = kh + (size_t)bh * SSQ * DDIM;
    int tid = threadIdx.x;
    int lane = tid & 63, w = tid >> 6;
    int wm = w >> 1, wn = w & 1;
    int rbase0 = blockIdx.y * 128, cbase0 = blockIdx.x * 128;
    int rbase = rbase0 + wm * 64;
    int cbase = cbase0 + wn * 64;
    int lr = lane & 15, lg = lane >> 4;
    f32x4 acc[4][4] = {};
#pragma unroll
    for (int k0 = 0; k0 < DDIM; k0 += 32) {
        bf16x8 a[4], bfr[4];
#pragma unroll
        for (int i = 0; i < 4; i++)
            a[i] = ld8(Q + (size_t)(rbase + i * 16 + lr) * DDIM + k0 + lg * 8);
#pragma unroll
        for (int j = 0; j < 4; j++)
            bfr[j] = ld8(K + (size_t)(cbase + j * 16 + lr) * DDIM + k0 + lg * 8);
#pragma unroll
        for (int i = 0; i < 4; i++)
#pragma unroll
            for (int j = 0; j < 4; j++)
                acc[i][j] = mfma16(a[i], bfr[j], acc[i][j]);
    }
    // fragment -> LDS (local tile coords)
#pragma unroll
    for (int i = 0; i < 4; i++)
#pragma unroll
        for (int j = 0; j < 4; j++) {
            int col = wn * 64 + j * 16 + lr;
#pragma unroll
            for (int e = 0; e < 4; e++) {
                int row = wm * 64 + i * 16 + lg * 4 + e;
                sl[row * 128 + col] = acc[i][j][e];
            }
        }
    __syncthreads();

    const float* pbh = pb + (size_t)h * SSQ * SSQ;
    const float* mb  = mask + (size_t)b * SSQ * SSQ;
    const float* pr  = prev + (size_t)bh * SSQ * SSQ;
    float* ob = out + (size_t)bh * SSQ * SSQ;
    int l31 = lane & 31;
    // 16 iterations: each half-wave (32 lanes) covers one full row x 128 cols
#pragma unroll 4
    for (int it = 0; it < 16; ++it) {
        int flat = it * 256 + tid;       // float4 index within 128x128 tile
        int rl = flat >> 5;              // local row 0..127
        int c4 = flat & 31;              // float4 col index
        int row = rbase0 + rl;
        int col = cbase0 + c4 * 4;
        size_t idx = (size_t)row * SSQ + col;
        f32x4 s4 = *(const f32x4*)(sl + rl * 128 + c4 * 4);
        f32x4 p4 = *(const f32x4*)(pbh + idx);
        f32x4 m4 = *(const f32x4*)(mb + idx);
        f32x4 r4 = *(const f32x4*)(pr + idx);
        f32x4 o4;
#pragma unroll
        for (int c = 0; c < 4; c++)
            o4[c] = (s4[c] + p4[c]) * 0.125f + m4[c] + r4[c];
        *(f32x4*)(ob + idx) = o4;
        // per-row (128-col chunk) partial max & sumexp across the 32-lane half
        float mx = fmaxf(fmaxf(o4[0], o4[1]), fmaxf(o4[2], o4[3]));
#pragma unroll
        for (int off = 16; off >= 1; off >>= 1) mx = fmaxf(mx, __shfl_xor(mx, off));
        float se = 0.f;
#pragma unroll
        for (int c = 0; c < 4; c++) se += __expf(o4[c] - mx);
#pragma unroll
        for (int off = 16; off >= 1; off >>= 1) se += __shfl_xor(se, off);
        if (l31 == 0) {
            size_t pidx = ((size_t)bh * 8 + blockIdx.x) * SSQ + row;
            pm[pidx] = mx;
            pl[pidx] = se;
        }
    }
}

// ---------------- combine partial stats: 8 col-blocks per row ----------------
__global__ __launch_bounds__(256) void stats_reduce(
        const float* __restrict__ pm, const float* __restrict__ pl,
        float* __restrict__ mrow, float* __restrict__ lrow) {
    int r = blockIdx.x * 256 + threadIdx.x;    // 0..65535 = bh*1024+row
    int bh = r >> 10, row = r & 1023;
    float mv[8];
    float m = -3.4e38f;
#pragma unroll
    for (int cb = 0; cb < 8; cb++) {
        mv[cb] = pm[((size_t)bh * 8 + cb) * SSQ + row];
        m = fmaxf(m, mv[cb]);
    }
    float l = 0.f;
#pragma unroll
    for (int cb = 0; cb < 8; cb++)
        l += pl[((size_t)bh * 8 + cb) * SSQ + row] * __expf(mv[cb] - m);
    mrow[r] = m;
    lrow[r] = l;
}

// ---------------- PV: ctx[s][h*64+d] = softmax(scores) @ v ----------------
__global__ __launch_bounds__(256) void pv_ctx(
        const float* __restrict__ sc, const float* __restrict__ mrow,
        const float* __restrict__ lrow, const u16* __restrict__ vt,
        u16* __restrict__ ctx) {
    int bh = blockIdx.y;
    int b = bh >> 4, h = bh & 15;
    int lane = threadIdx.x & 63, w = threadIdx.x >> 6;
    int lr = lane & 15, lg = lane >> 4;
    int rbase = blockIdx.x * 128 + w * 32;
    const float* sb = sc + (size_t)bh * SSQ * SSQ;
    const u16* vb = vt + (size_t)bh * DDIM * SSQ;
    float mr[2];
    mr[0] = mrow[(size_t)bh * SSQ + rbase + lr];
    mr[1] = mrow[(size_t)bh * SSQ + rbase + 16 + lr];
    f32x4 acc[2][4] = {};
    for (int k0 = 0; k0 < SSQ; k0 += 32) {
        bf16x8 a[2];
#pragma unroll
        for (int am = 0; am < 2; am++) {
            const float* sp = sb + (size_t)(rbase + am * 16 + lr) * SSQ + k0 + lg * 8;
            f32x4 x0 = *(const f32x4*)sp;
            f32x4 x1 = *(const f32x4*)(sp + 4);
            short8 pk;
#pragma unroll
            for (int c = 0; c < 4; c++) pk[c]     = (short)f2b(__expf(x0[c] - mr[am]));
#pragma unroll
            for (int c = 0; c < 4; c++) pk[4 + c] = (short)f2b(__expf(x1[c] - mr[am]));
            a[am] = __builtin_bit_cast(bf16x8, pk);
        }
        bf16x8 bfr[4];
#pragma unroll
        for (int j = 0; j < 4; j++)
            bfr[j] = ld8(vb + (size_t)(j * 16 + lr) * SSQ + k0 + lg * 8);
#pragma unroll
        for (int am = 0; am < 2; am++)
#pragma unroll
            for (int j = 0; j < 4; j++)
                acc[am][j] = mfma16(a[am], bfr[j], acc[am][j]);
    }
    float linv[2][4];
#pragma unroll
    for (int am = 0; am < 2; am++)
#pragma unroll
        for (int e = 0; e < 4; e++)
            linv[am][e] = 1.f / lrow[(size_t)bh * SSQ + rbase + am * 16 + lg * 4 + e];
#pragma unroll
    for (int am = 0; am < 2; am++)
#pragma unroll
        for (int j = 0; j < 4; j++) {
            int d = j * 16 + lr;
#pragma unroll
            for (int e = 0; e < 4; e++) {
                int row = rbase + am * 16 + lg * 4 + e;
                ctx[((size_t)(b * SSQ + row)) * HHD + h * DDIM + d] =
                    f2b(acc[am][j][e] * linv[am][e]);
            }
        }
}

// ---------------- output projection ----------------
__global__ __launch_bounds__(256) void gemm_out(
        const u16* __restrict__ ctxb, const u16* __restrict__ WtO,
        const float* __restrict__ bo, float* __restrict__ out) {
    int lane = threadIdx.x & 63, w = threadIdx.x >> 6;
    int wm = w >> 1, wn = w & 1;
    int rbase = blockIdx.y * 128 + wm * 64;
    int cbase = blockIdx.x * 128 + wn * 64;
    int lr = lane & 15, lg = lane >> 4;
    f32x4 acc[4][4] = {};
    for (int k0 = 0; k0 < HHD; k0 += 32) {
        bf16x8 a[4], b[4];
#pragma unroll
        for (int i = 0; i < 4; i++)
            a[i] = ld8(ctxb + (size_t)(rbase + i * 16 + lr) * HHD + k0 + lg * 8);
#pragma unroll
        for (int j = 0; j < 4; j++)
            b[j] = ld8(WtO + (size_t)(cbase + j * 16 + lr) * HHD + k0 + lg * 8);
#pragma unroll
        for (int i = 0; i < 4; i++)
#pragma unroll
            for (int j = 0; j < 4; j++)
                acc[i][j] = mfma16(a[i], b[j], acc[i][j]);
    }
#pragma unroll
    for (int i = 0; i < 4; i++)
#pragma unroll
        for (int j = 0; j < 4; j++) {
            int col = cbase + j * 16 + lr;
            float bval = bo[col];
#pragma unroll
            for (int e = 0; e < 4; e++) {
                int row = rbase + i * 16 + lg * 4 + e;
                out[(size_t)row * HHD + col] = acc[i][j][e] + bval;
            }
        }
}

extern "C" void kernel_launch(void* const* d_in, const int* in_sizes, int n_in,
                              void* d_out, int out_size, void* d_ws, size_t ws_size,
                              hipStream_t stream) {
    const float* key   = (const float*)d_in[0];
    const float* value = (const float*)d_in[1];
    const float* query = (const float*)d_in[2];
    const float* mask  = (const float*)d_in[3];
    const float* pb    = (const float*)d_in[4];
    const float* prev  = (const float*)d_in[5];
    const float* Wq    = (const float*)d_in[6];
    const float* bq    = (const float*)d_in[7];
    const float* Wk    = (const float*)d_in[8];
    const float* bk    = (const float*)d_in[9];
    const float* Wv    = (const float*)d_in[10];
    const float* bv    = (const float*)d_in[11];
    const float* Wo    = (const float*)d_in[12];
    const float* bo    = (const float*)d_in[13];

    u16* Xb  = (u16*)d_ws;                      // 3 * 4M bf16
    u16* Wt  = Xb + (size_t)3 * MM * HHD;       // 4 * 1M bf16
    u16* qh  = Wt + (size_t)4 * HHD * HHD;      // 4M
    u16* kh  = qh + (size_t)MM * HHD;           // 4M
    u16* vt  = kh + (size_t)MM * HHD;           // 4M
    u16* ctx = vt + (size_t)MM * HHD;           // 4M
    float* mrow = (float*)(ctx + (size_t)MM * HHD);   // 64K f32
    float* lrow = mrow + (size_t)64 * SSQ;            // 64K f32
    float* pm   = lrow + (size_t)64 * SSQ;            // 512K f32 partial max
    float* pl   = pm + (size_t)64 * 8 * SSQ;          // 512K f32 partial sumexp

    float* out0 = (float*)d_out;
    float* sc   = out0 + OUT0_ELEMS;            // prev_attn_out region

    conv_x<<<dim3(4096, 1, 3), 256, 0, stream>>>(query, key, value, Xb);
    conv_wt<<<dim3(32, 32, 4), dim3(32, 8), 0, stream>>>(Wq, Wk, Wv, Wo, Wt);
    gemm_xw<<<dim3(8, 32, 3), 256, 0, stream>>>(Xb, Wt, bq, bk, bv, qh, kh, vt);
    attn_scores<<<dim3(8, 8, 64), 256, 0, stream>>>(qh, kh, pb, mask, prev, sc, pm, pl);
    stats_reduce<<<dim3(256), 256, 0, stream>>>(pm, pl, mrow, lrow);
    pv_ctx<<<dim3(8, 64), 256, 0, stream>>>(sc, mrow, lrow, vt, ctx);
    gemm_out<<<dim3(8, 32), 256, 0, stream>>>(ctx, Wt + (size_t)3 * HHD * HHD, bo, out0);
}